// Round 1
// baseline (199.283 us; speedup 1.0000x reference)
//
#include <hip/hip_runtime.h>

// ROI Align (crop_and_resize-style bilinear), fp32.
// fmaps: [8,128,128,256], rois: [8,128,4] (x1,y1,x2,y2), out: [8,128,7,7,256]
// One thread = one float4 of channels at one output pixel.
// 64 lanes/pixel -> coalesced 1KB wave loads per corner, coalesced float4 store.

#define NBATCH 8
#define NROI   128
#define FH     128
#define FW     128
#define NC     256
#define OH     7
#define OW     7

__global__ __launch_bounds__(256) void roi_align_kernel(
    const float* __restrict__ fmaps,
    const float* __restrict__ rois,
    float* __restrict__ out)
{
    const int gid = blockIdx.x * 256 + threadIdx.x;
    const int c4    = gid & 63;          // which float4 of the 256 channels
    const int pixel = gid >> 6;          // (b, roi, i, j) flattened

    const int j   = pixel % OW;
    int t         = pixel / OW;
    const int i   = t % OH;
    t             = t / OH;
    const int roi = t % NROI;
    const int b   = t / NROI;

    const float* r = rois + (size_t)(b * NROI + roi) * 4;
    const float x1 = r[0], y1 = r[1], x2 = r[2], y2 = r[3];

    const float Hf = 128.0f, Wf = 128.0f;
    // Replicate reference op order exactly: (v * Hf) / (Hf - 1)
    const float by1 = y1 * Hf / (Hf - 1.0f);
    const float bx1 = x1 * Wf / (Wf - 1.0f);
    const float by2 = y2 * Hf / (Hf - 1.0f);
    const float bx2 = x2 * Wf / (Wf - 1.0f);

    // in_y = by1*(Hf-1) + i * ((by2-by1)*(Hf-1)/(o_h-1))
    float in_y = by1 * (Hf - 1.0f) + (float)i * ((by2 - by1) * (Hf - 1.0f) / 6.0f);
    float in_x = bx1 * (Wf - 1.0f) + (float)j * ((bx2 - bx1) * (Wf - 1.0f) / 6.0f);

    const bool valid = (in_y >= 0.0f) & (in_y <= Hf - 1.0f) &
                       (in_x >= 0.0f) & (in_x <= Wf - 1.0f);

    in_y = fminf(fmaxf(in_y, 0.0f), Hf - 1.0f);
    in_x = fminf(fmaxf(in_x, 0.0f), Wf - 1.0f);

    const float y0f = floorf(in_y);
    const float x0f = floorf(in_x);
    const float ly  = in_y - y0f;
    const float lx  = in_x - x0f;
    const int y0  = (int)y0f;
    const int x0  = (int)x0f;
    const int y1i = min(y0 + 1, FH - 1);
    const int x1i = min(x0 + 1, FW - 1);

    // fmap for this batch, viewed as float4: index (y*FW + x)*64 + c4
    const float4* __restrict__ f =
        (const float4*)(fmaps + (size_t)b * FH * FW * NC);

    const float4 tl = f[(y0  * FW + x0 ) * 64 + c4];
    const float4 tr = f[(y0  * FW + x1i) * 64 + c4];
    const float4 bl = f[(y1i * FW + x0 ) * 64 + c4];
    const float4 br = f[(y1i * FW + x1i) * 64 + c4];

    const float m = valid ? 1.0f : 0.0f;

    float4 o;
    {
        float top, bot;
        top = tl.x + (tr.x - tl.x) * lx;
        bot = bl.x + (br.x - bl.x) * lx;
        o.x = (top + (bot - top) * ly) * m;
        top = tl.y + (tr.y - tl.y) * lx;
        bot = bl.y + (br.y - bl.y) * lx;
        o.y = (top + (bot - top) * ly) * m;
        top = tl.z + (tr.z - tl.z) * lx;
        bot = bl.z + (br.z - bl.z) * lx;
        o.z = (top + (bot - top) * ly) * m;
        top = tl.w + (tr.w - tl.w) * lx;
        bot = bl.w + (br.w - bl.w) * lx;
        o.w = (top + (bot - top) * ly) * m;
    }

    ((float4*)out)[gid] = o;
}

extern "C" void kernel_launch(void* const* d_in, const int* in_sizes, int n_in,
                              void* d_out, int out_size, void* d_ws, size_t ws_size,
                              hipStream_t stream) {
    const float* fmaps = (const float*)d_in[0];
    const float* rois  = (const float*)d_in[1];
    float* out = (float*)d_out;

    // total float4 threads: 8*128*7*7 pixels * 64 = 3,211,264 -> 12,544 blocks
    const int total = NBATCH * NROI * OH * OW * 64;
    roi_align_kernel<<<total / 256, 256, 0, stream>>>(fmaps, rois, out);
}